// Round 7
// baseline (217.336 us; speedup 1.0000x reference)
//
#include <hip/hip_runtime.h>
#include <math.h>

#define N_NODES 25000
#define N_EDGES 400000
#define EMBED   128
#define HEADS   8
#define DK      16
#define NBLK    98        // ceil(25000/256)

typedef __attribute__((ext_vector_type(8))) short bf16x8;
typedef __attribute__((ext_vector_type(4))) float f32x4;
typedef unsigned int uint;
typedef unsigned short ushort;

__device__ inline uint pack2_bf16(float a, float b) {
    union { float f; uint u; } ua, ub;
    ua.f = a; ub.f = b;
    uint ra = (ua.u + 0x7FFFu + ((ua.u >> 16) & 1u)) >> 16;
    uint rb = (ub.u + 0x7FFFu + ((ub.u >> 16) & 1u)) >> 16;
    return (ra & 0xFFFFu) | (rb << 16);
}
__device__ inline ushort cvt_bf16(float a) {
    union { float f; uint u; } ua; ua.f = a;
    return (ushort)((ua.u + 0x7FFFu + ((ua.u >> 16) & 1u)) >> 16);
}
__device__ inline float bf16_lo(uint u) {
    union { uint u; float f; } x; x.u = u << 16; return x.f;
}
__device__ inline float bf16_hi(uint u) {
    union { uint u; float f; } x; x.u = u & 0xFFFF0000u; return x.f;
}

// ---------------------------------------------------------------------------
// Convert x (N*128) and the four 128x128 weights to bf16; zero deg inline.
// ---------------------------------------------------------------------------
#define NX (N_NODES * 128)
__global__ __launch_bounds__(256) void convert_all(
    const float* __restrict__ x,
    const float* __restrict__ Wq, const float* __restrict__ Wk,
    const float* __restrict__ Wv, const float* __restrict__ Wo,
    ushort* __restrict__ xb, ushort* __restrict__ wb, int* __restrict__ deg)
{
    int i = blockIdx.x * 256 + threadIdx.x;   // pair index
    if (i < N_NODES) deg[i] = 0;
    int base = i * 2;
    if (base < NX) {
        float2 v = *reinterpret_cast<const float2*>(x + base);
        reinterpret_cast<uint*>(xb)[i] = pack2_bf16(v.x, v.y);
    } else {
        int j = base - NX;
        if (j < 4 * 16384) {
            const float* src = (j < 16384) ? Wq + j
                             : (j < 32768) ? Wk + (j - 16384)
                             : (j < 49152) ? Wv + (j - 32768)
                             :               Wo + (j - 49152);
            float2 v = *reinterpret_cast<const float2*>(src);
            reinterpret_cast<uint*>(wb)[j >> 1] = pack2_bf16(v.x, v.y);
        }
    }
}

// ---------------------------------------------------------------------------
// MFMA GEMM for Q/K/V + degree histogram.
// blockIdx.y in {0,1,2}: GEMM with weights/bias q/k/v; y==3: histogram.
// Q -> Qb [row*128+col] bf16. K/V interleaved in KVu:
//   ushort idx = row*256 + (col>>1)*4 + (col&1) + (V ? 2 : 0)
// ---------------------------------------------------------------------------
__global__ __launch_bounds__(256) void gemm_qkv_deg(
    const ushort* __restrict__ A, const ushort* __restrict__ Wall,
    const float* __restrict__ bq, const float* __restrict__ bk,
    const float* __restrict__ bv,
    ushort* __restrict__ Qb, ushort* __restrict__ KVu,
    const int* __restrict__ ei, int* __restrict__ deg,
    int M)
{
    const int which = blockIdx.y;
    if (which == 3) {
        int t = blockIdx.x * 256 + threadIdx.x;
        int e = t * 4;
        if (e + 3 < N_EDGES) {
            int4 d = *reinterpret_cast<const int4*>(ei + e);
            atomicAdd(&deg[d.x], 1);
            atomicAdd(&deg[d.y], 1);
            atomicAdd(&deg[d.z], 1);
            atomicAdd(&deg[d.w], 1);
        } else {
            for (; e < N_EDGES && e < t * 4 + 4; ++e)
                atomicAdd(&deg[ei[e]], 1);
        }
        return;
    }

    const ushort* W = Wall + which * 16384;
    const float* bias = (which == 0) ? bq : (which == 1) ? bk : bv;

    const int lane = threadIdx.x & 63;
    const int wave = threadIdx.x >> 6;
    const int ml   = lane & 15;
    const int quad = lane >> 4;
    const int m0   = blockIdx.x * 64 + wave * 16;

    int arow = m0 + ml; if (arow >= M) arow = M - 1;
    const ushort* ap = A + arow * 128 + quad * 8;

    f32x4 acc[8];
#pragma unroll
    for (int ct = 0; ct < 8; ++ct) acc[ct] = (f32x4){0.f, 0.f, 0.f, 0.f};

#pragma unroll
    for (int ks = 0; ks < 128; ks += 32) {
        bf16x8 af = *reinterpret_cast<const bf16x8*>(ap + ks);
#pragma unroll
        for (int ct = 0; ct < 8; ++ct) {
            bf16x8 bf = *reinterpret_cast<const bf16x8*>(
                W + (ct * 16 + ml) * 128 + ks + quad * 8);
            acc[ct] = __builtin_amdgcn_mfma_f32_16x16x32_bf16(af, bf, acc[ct], 0, 0, 0);
        }
    }

#pragma unroll
    for (int ct = 0; ct < 8; ++ct) {
        int col = ct * 16 + ml;
        float bv_ = bias[col];
#pragma unroll
        for (int r = 0; r < 4; ++r) {
            int row = m0 + quad * 4 + r;
            if (row >= M) continue;
            ushort v = cvt_bf16(acc[ct][r] + bv_);
            if (which == 0) {
                Qb[row * 128 + col] = v;
            } else {
                KVu[row * 256 + (col >> 1) * 4 + (col & 1) + ((which == 2) ? 2 : 0)] = v;
            }
        }
    }
}

// Final projection: A bf16 [M,128] @ W^T + bias -> fp32 out
__global__ __launch_bounds__(256) void gemm_out(
    const ushort* __restrict__ A, const ushort* __restrict__ W,
    const float* __restrict__ bias, float* __restrict__ C, int M)
{
    const int lane = threadIdx.x & 63;
    const int wave = threadIdx.x >> 6;
    const int ml   = lane & 15;
    const int quad = lane >> 4;
    const int m0   = blockIdx.x * 64 + wave * 16;

    int arow = m0 + ml; if (arow >= M) arow = M - 1;
    const ushort* ap = A + arow * 128 + quad * 8;

    f32x4 acc[8];
#pragma unroll
    for (int ct = 0; ct < 8; ++ct) acc[ct] = (f32x4){0.f, 0.f, 0.f, 0.f};

#pragma unroll
    for (int ks = 0; ks < 128; ks += 32) {
        bf16x8 af = *reinterpret_cast<const bf16x8*>(ap + ks);
#pragma unroll
        for (int ct = 0; ct < 8; ++ct) {
            bf16x8 bf = *reinterpret_cast<const bf16x8*>(
                W + (ct * 16 + ml) * 128 + ks + quad * 8);
            acc[ct] = __builtin_amdgcn_mfma_f32_16x16x32_bf16(af, bf, acc[ct], 0, 0, 0);
        }
    }

#pragma unroll
    for (int ct = 0; ct < 8; ++ct) {
        int col = ct * 16 + ml;
        float bv_ = bias[col];
#pragma unroll
        for (int r = 0; r < 4; ++r) {
            int row = m0 + quad * 4 + r;
            if (row < M)
                C[row * 128 + col] = acc[ct][r] + bv_;
        }
    }
}

// ---------------------------------------------------------------------------
// Hierarchical exclusive scan (3 small kernels) + scatter (int2 {e, src}).
// ---------------------------------------------------------------------------
__global__ __launch_bounds__(256) void scan_blocks(
    const int* __restrict__ deg, int* __restrict__ excl, int* __restrict__ bsum)
{
    __shared__ int sh[256];
    int t = threadIdx.x;
    int gid = blockIdx.x * 256 + t;
    int v = (gid < N_NODES) ? deg[gid] : 0;
    sh[t] = v;
    __syncthreads();
#pragma unroll
    for (int off = 1; off < 256; off <<= 1) {
        int u = (t >= off) ? sh[t - off] : 0;
        __syncthreads();
        sh[t] += u;
        __syncthreads();
    }
    if (gid < N_NODES) excl[gid] = sh[t] - v;
    if (t == 255) bsum[blockIdx.x] = sh[255];
}

__global__ __launch_bounds__(128) void scan_tops(
    const int* __restrict__ bsum, int* __restrict__ bbase)
{
    __shared__ int sh[128];
    int t = threadIdx.x;
    int v = (t < NBLK) ? bsum[t] : 0;
    sh[t] = v;
    __syncthreads();
#pragma unroll
    for (int off = 1; off < 128; off <<= 1) {
        int u = (t >= off) ? sh[t - off] : 0;
        __syncthreads();
        sh[t] += u;
        __syncthreads();
    }
    if (t < NBLK) bbase[t] = sh[t] - v;
}

__global__ __launch_bounds__(256) void scan_apply(
    int* __restrict__ excl, const int* __restrict__ bbase,
    int* __restrict__ cursor)
{
    int t = threadIdx.x;
    int gid = blockIdx.x * 256 + t;
    if (gid < N_NODES) {
        int o = excl[gid] + bbase[blockIdx.x];
        excl[gid] = o;         // excl buffer IS offsets
        cursor[gid] = o;
    }
    if (blockIdx.x == 0 && t == 0) excl[N_NODES] = N_EDGES;
}

__global__ __launch_bounds__(256) void scatter_edges(
    const int* __restrict__ ei, int* __restrict__ cursor,
    int2* __restrict__ csr2)
{
    int e = blockIdx.x * 256 + threadIdx.x;
    if (e >= N_EDGES) return;
    int dst = ei[e];
    int src = ei[N_EDGES + e];
    int pos = atomicAdd(&cursor[dst], 1);
    csr2[pos] = make_int2(e, src);
}

// ---------------------------------------------------------------------------
// Fused attention v6: TWO waves per node, each processing half the CSR range
// with the proven 4-edge unroll; partials (z, accx, accy) are purely additive
// (exp without max-subtraction) -> one LDS combine + __syncthreads.
// Lane l holds dims {2l,2l+1}; head h = l>>3. One uint2 KV load per edge.
// ---------------------------------------------------------------------------
__global__ __launch_bounds__(256) void fused_attn(
    const ushort* __restrict__ Q2, const uint2* __restrict__ KV,
    const float* __restrict__ attn_bias,
    const int* __restrict__ offsets, const int2* __restrict__ csr2,
    float* __restrict__ logits, ushort* __restrict__ AGG)
{
    __shared__ float shx[4][64], shy[4][64], shz[4][64];

    const int lane = threadIdx.x & 63;
    const int wid  = threadIdx.x >> 6;
    const int n    = blockIdx.x * 2 + (wid >> 1);   // 2 nodes per block
    const int sub  = wid & 1;                       // which half-range
    const int h = lane >> 3;

    const int nstart = offsets[n], nend = offsets[n + 1];
    const int tot = nend - nstart;
    const int mid = nstart + ((tot + 1) >> 1);
    const int start = sub ? mid : nstart;
    const int end   = sub ? nend : mid;

    uint qu = reinterpret_cast<const uint*>(Q2)[n * 64 + lane];
    float qx = bf16_lo(qu), qy = bf16_hi(qu);

    float z = 0.f, accx = 0.f, accy = 0.f;

    for (int base = start; base < end; base += 64) {
        int cnt = end - base; if (cnt > 64) cnt = 64;
        int e_l = 0, s_l = 0;
        if (lane < cnt) {
            int2 es = csr2[base + lane];
            e_l = es.x; s_l = es.y;
        }
        int j = 0;
        for (; j + 3 < cnt; j += 4) {
            int e0 = __shfl(e_l, j, 64),     e1 = __shfl(e_l, j + 1, 64);
            int e2 = __shfl(e_l, j + 2, 64), e3 = __shfl(e_l, j + 3, 64);
            int s0 = __shfl(s_l, j, 64),     s1 = __shfl(s_l, j + 1, 64);
            int s2 = __shfl(s_l, j + 2, 64), s3 = __shfl(s_l, j + 3, 64);
            uint2 kv0 = KV[s0 * 64 + lane], kv1 = KV[s1 * 64 + lane];
            uint2 kv2 = KV[s2 * 64 + lane], kv3 = KV[s3 * 64 + lane];
            float b0 = attn_bias[e0 * 8 + h], b1 = attn_bias[e1 * 8 + h];
            float b2 = attn_bias[e2 * 8 + h], b3 = attn_bias[e3 * 8 + h];

            float d0 = qx * bf16_lo(kv0.x) + qy * bf16_hi(kv0.x);
            float d1 = qx * bf16_lo(kv1.x) + qy * bf16_hi(kv1.x);
            float d2 = qx * bf16_lo(kv2.x) + qy * bf16_hi(kv2.x);
            float d3 = qx * bf16_lo(kv3.x) + qy * bf16_hi(kv3.x);
#pragma unroll
            for (int off = 1; off < 8; off <<= 1) {
                d0 += __shfl_xor(d0, off, 64);
                d1 += __shfl_xor(d1, off, 64);
                d2 += __shfl_xor(d2, off, 64);
                d3 += __shfl_xor(d3, off, 64);
            }
            float l0 = 0.25f * d0 + b0, l1 = 0.25f * d1 + b1;
            float l2 = 0.25f * d2 + b2, l3 = 0.25f * d3 + b3;
            if ((lane & 7) == 0) {
                logits[e0 * 8 + h] = l0;
                logits[e1 * 8 + h] = l1;
                logits[e2 * 8 + h] = l2;
                logits[e3 * 8 + h] = l3;
            }
            float p0 = __expf(l0), p1 = __expf(l1);
            float p2 = __expf(l2), p3 = __expf(l3);
            z += (p0 + p1) + (p2 + p3);
            accx += p0 * bf16_lo(kv0.y) + p1 * bf16_lo(kv1.y)
                  + p2 * bf16_lo(kv2.y) + p3 * bf16_lo(kv3.y);
            accy += p0 * bf16_hi(kv0.y) + p1 * bf16_hi(kv1.y)
                  + p2 * bf16_hi(kv2.y) + p3 * bf16_hi(kv3.y);
        }
        for (; j < cnt; ++j) {
            int e0 = __shfl(e_l, j, 64);
            int s0 = __shfl(s_l, j, 64);
            uint2 kv0 = KV[s0 * 64 + lane];
            float b0 = attn_bias[e0 * 8 + h];
            float d0 = qx * bf16_lo(kv0.x) + qy * bf16_hi(kv0.x);
#pragma unroll
            for (int off = 1; off < 8; off <<= 1) d0 += __shfl_xor(d0, off, 64);
            float l0 = 0.25f * d0 + b0;
            if ((lane & 7) == 0) logits[e0 * 8 + h] = l0;
            float p0 = __expf(l0);
            z += p0;
            accx += p0 * bf16_lo(kv0.y);
            accy += p0 * bf16_hi(kv0.y);
        }
    }

    shx[wid][lane] = accx;
    shy[wid][lane] = accy;
    shz[wid][lane] = z;
    __syncthreads();

    if (sub == 0) {
        float ax = shx[wid][lane] + shx[wid + 1][lane];
        float ay = shy[wid][lane] + shy[wid + 1][lane];
        float zz = shz[wid][lane] + shz[wid + 1][lane];
        float inv = (zz > 0.f) ? 1.f / zz : 0.f;
        reinterpret_cast<uint*>(AGG)[n * 64 + lane] = pack2_bf16(ax * inv, ay * inv);
    }
}

// ---------------------------------------------------------------------------
extern "C" void kernel_launch(void* const* d_in, const int* in_sizes, int n_in,
                              void* d_out, int out_size, void* d_ws, size_t ws_size,
                              hipStream_t stream)
{
    const float* x         = (const float*)d_in[0];
    const int*   ei        = (const int*)  d_in[1];
    const float* attn_bias = (const float*)d_in[2];
    const float* Wq = (const float*)d_in[3];
    const float* bq = (const float*)d_in[4];
    const float* Wk = (const float*)d_in[5];
    const float* bk = (const float*)d_in[6];
    const float* Wv = (const float*)d_in[7];
    const float* bv = (const float*)d_in[8];
    const float* Wo = (const float*)d_in[9];
    const float* bo = (const float*)d_in[10];

    float* out    = (float*)d_out;                // [N,128]
    float* logits = out + N_NODES * EMBED;        // [E,8] (output 1)

    ushort* xb   = (ushort*)d_ws;                 // N*128
    ushort* wb   = xb + NX;                       // 4*16384 (Wq,Wk,Wv,Wo)
    ushort* Qb   = wb + 4 * 16384;                // N*128
    ushort* KVu  = Qb + NX;                       // N*256 (K/V interleaved)
    ushort* AGGb = KVu + 2 * NX;                  // N*128
    int* deg     = (int*)(AGGb + NX);
    int* offsets = deg + N_NODES;                 // N+1 (also excl buffer)
    int* cursor  = offsets + N_NODES + 1;
    int2* csr2   = (int2*)(cursor + N_NODES);     // E pairs {edge, src}
    int* bsum    = (int*)(csr2 + N_EDGES);        // NBLK
    int* bbase   = bsum + NBLK;                   // NBLK

    int npairs = (NX + 4 * 16384) / 2;
    convert_all<<<(npairs + 255) / 256, 256, 0, stream>>>(x, Wq, Wk, Wv, Wo, xb, wb, deg);

    int gblocks = (N_NODES + 63) / 64;            // 391
    dim3 qkvgrid(gblocks, 4);                     // y=0..2 gemm, y=3 histogram
    gemm_qkv_deg<<<qkvgrid, 256, 0, stream>>>(xb, wb, bq, bk, bv, Qb, KVu,
                                              ei, deg, N_NODES);

    scan_blocks<<<NBLK, 256, 0, stream>>>(deg, offsets, bsum);
    scan_tops<<<1, 128, 0, stream>>>(bsum, bbase);
    scan_apply<<<NBLK, 256, 0, stream>>>(offsets, bbase, cursor);
    scatter_edges<<<(N_EDGES + 255) / 256, 256, 0, stream>>>(ei, cursor, csr2);

    fused_attn<<<N_NODES / 2, 256, 0, stream>>>(Qb, (const uint2*)KVu, attn_bias,
                                                offsets, csr2, logits, AGGb);

    gemm_out<<<gblocks, 256, 0, stream>>>(AGGb, wb + 3 * 16384, bo, out, N_NODES);
}

// Round 8
// 210.140 us; speedup vs baseline: 1.0342x; 1.0342x over previous
//
#include <hip/hip_runtime.h>
#include <math.h>

#define N_NODES 25000
#define N_EDGES 400000
#define EMBED   128
#define HEADS   8
#define DK      16
#define NBLK    98        // ceil(25000/256)

typedef __attribute__((ext_vector_type(8))) short bf16x8;
typedef __attribute__((ext_vector_type(4))) float f32x4;
typedef unsigned int uint;
typedef unsigned short ushort;

__device__ inline uint pack2_bf16(float a, float b) {
    union { float f; uint u; } ua, ub;
    ua.f = a; ub.f = b;
    uint ra = (ua.u + 0x7FFFu + ((ua.u >> 16) & 1u)) >> 16;
    uint rb = (ub.u + 0x7FFFu + ((ub.u >> 16) & 1u)) >> 16;
    return (ra & 0xFFFFu) | (rb << 16);
}
__device__ inline ushort cvt_bf16(float a) {
    union { float f; uint u; } ua; ua.f = a;
    return (ushort)((ua.u + 0x7FFFu + ((ua.u >> 16) & 1u)) >> 16);
}
__device__ inline float bf16_lo(uint u) {
    union { uint u; float f; } x; x.u = u << 16; return x.f;
}
__device__ inline float bf16_hi(uint u) {
    union { uint u; float f; } x; x.u = u & 0xFFFF0000u; return x.f;
}

// ---------------------------------------------------------------------------
// Convert x (N*128) and the four 128x128 weights to bf16; zero deg inline.
// ---------------------------------------------------------------------------
#define NX (N_NODES * 128)
__global__ __launch_bounds__(256) void convert_all(
    const float* __restrict__ x,
    const float* __restrict__ Wq, const float* __restrict__ Wk,
    const float* __restrict__ Wv, const float* __restrict__ Wo,
    ushort* __restrict__ xb, ushort* __restrict__ wb, int* __restrict__ deg)
{
    int i = blockIdx.x * 256 + threadIdx.x;   // pair index
    if (i < N_NODES) deg[i] = 0;
    int base = i * 2;
    if (base < NX) {
        float2 v = *reinterpret_cast<const float2*>(x + base);
        reinterpret_cast<uint*>(xb)[i] = pack2_bf16(v.x, v.y);
    } else {
        int j = base - NX;
        if (j < 4 * 16384) {
            const float* src = (j < 16384) ? Wq + j
                             : (j < 32768) ? Wk + (j - 16384)
                             : (j < 49152) ? Wv + (j - 32768)
                             :               Wo + (j - 49152);
            float2 v = *reinterpret_cast<const float2*>(src);
            reinterpret_cast<uint*>(wb)[j >> 1] = pack2_bf16(v.x, v.y);
        }
    }
}

// ---------------------------------------------------------------------------
// MFMA GEMM for Q/K/V + degree histogram.
// blockIdx.y in {0,1,2}: GEMM with weights/bias q/k/v; y==3: histogram.
// All outputs plain row-major bf16 [row*128+col].
// ---------------------------------------------------------------------------
__global__ __launch_bounds__(256) void gemm_qkv_deg(
    const ushort* __restrict__ A, const ushort* __restrict__ Wall,
    const float* __restrict__ bq, const float* __restrict__ bk,
    const float* __restrict__ bv,
    ushort* __restrict__ Qb, ushort* __restrict__ Kb, ushort* __restrict__ Vb,
    const int* __restrict__ ei, int* __restrict__ deg,
    int M)
{
    const int which = blockIdx.y;
    if (which == 3) {
        int t = blockIdx.x * 256 + threadIdx.x;
        int e = t * 4;
        if (e + 3 < N_EDGES) {
            int4 d = *reinterpret_cast<const int4*>(ei + e);
            atomicAdd(&deg[d.x], 1);
            atomicAdd(&deg[d.y], 1);
            atomicAdd(&deg[d.z], 1);
            atomicAdd(&deg[d.w], 1);
        } else {
            for (; e < N_EDGES && e < t * 4 + 4; ++e)
                atomicAdd(&deg[ei[e]], 1);
        }
        return;
    }

    const ushort* W = Wall + which * 16384;
    const float* bias = (which == 0) ? bq : (which == 1) ? bk : bv;
    ushort* C = (which == 0) ? Qb : (which == 1) ? Kb : Vb;

    const int lane = threadIdx.x & 63;
    const int wave = threadIdx.x >> 6;
    const int ml   = lane & 15;
    const int quad = lane >> 4;
    const int m0   = blockIdx.x * 64 + wave * 16;

    int arow = m0 + ml; if (arow >= M) arow = M - 1;
    const ushort* ap = A + arow * 128 + quad * 8;

    f32x4 acc[8];
#pragma unroll
    for (int ct = 0; ct < 8; ++ct) acc[ct] = (f32x4){0.f, 0.f, 0.f, 0.f};

#pragma unroll
    for (int ks = 0; ks < 128; ks += 32) {
        bf16x8 af = *reinterpret_cast<const bf16x8*>(ap + ks);
#pragma unroll
        for (int ct = 0; ct < 8; ++ct) {
            bf16x8 bf = *reinterpret_cast<const bf16x8*>(
                W + (ct * 16 + ml) * 128 + ks + quad * 8);
            acc[ct] = __builtin_amdgcn_mfma_f32_16x16x32_bf16(af, bf, acc[ct], 0, 0, 0);
        }
    }

#pragma unroll
    for (int ct = 0; ct < 8; ++ct) {
        int col = ct * 16 + ml;
        float bv_ = bias[col];
#pragma unroll
        for (int r = 0; r < 4; ++r) {
            int row = m0 + quad * 4 + r;
            if (row < M)
                C[row * 128 + col] = cvt_bf16(acc[ct][r] + bv_);
        }
    }
}

// Final projection: A bf16 [M,128] @ W^T + bias -> fp32 out
__global__ __launch_bounds__(256) void gemm_out(
    const ushort* __restrict__ A, const ushort* __restrict__ W,
    const float* __restrict__ bias, float* __restrict__ C, int M)
{
    const int lane = threadIdx.x & 63;
    const int wave = threadIdx.x >> 6;
    const int ml   = lane & 15;
    const int quad = lane >> 4;
    const int m0   = blockIdx.x * 64 + wave * 16;

    int arow = m0 + ml; if (arow >= M) arow = M - 1;
    const ushort* ap = A + arow * 128 + quad * 8;

    f32x4 acc[8];
#pragma unroll
    for (int ct = 0; ct < 8; ++ct) acc[ct] = (f32x4){0.f, 0.f, 0.f, 0.f};

#pragma unroll
    for (int ks = 0; ks < 128; ks += 32) {
        bf16x8 af = *reinterpret_cast<const bf16x8*>(ap + ks);
#pragma unroll
        for (int ct = 0; ct < 8; ++ct) {
            bf16x8 bf = *reinterpret_cast<const bf16x8*>(
                W + (ct * 16 + ml) * 128 + ks + quad * 8);
            acc[ct] = __builtin_amdgcn_mfma_f32_16x16x32_bf16(af, bf, acc[ct], 0, 0, 0);
        }
    }

#pragma unroll
    for (int ct = 0; ct < 8; ++ct) {
        int col = ct * 16 + ml;
        float bv_ = bias[col];
#pragma unroll
        for (int r = 0; r < 4; ++r) {
            int row = m0 + quad * 4 + r;
            if (row < M)
                C[row * 128 + col] = acc[ct][r] + bv_;
        }
    }
}

// ---------------------------------------------------------------------------
// Hierarchical exclusive scan (3 small kernels) + scatter (int2 {e, src}).
// ---------------------------------------------------------------------------
__global__ __launch_bounds__(256) void scan_blocks(
    const int* __restrict__ deg, int* __restrict__ excl, int* __restrict__ bsum)
{
    __shared__ int sh[256];
    int t = threadIdx.x;
    int gid = blockIdx.x * 256 + t;
    int v = (gid < N_NODES) ? deg[gid] : 0;
    sh[t] = v;
    __syncthreads();
#pragma unroll
    for (int off = 1; off < 256; off <<= 1) {
        int u = (t >= off) ? sh[t - off] : 0;
        __syncthreads();
        sh[t] += u;
        __syncthreads();
    }
    if (gid < N_NODES) excl[gid] = sh[t] - v;
    if (t == 255) bsum[blockIdx.x] = sh[255];
}

__global__ __launch_bounds__(128) void scan_tops(
    const int* __restrict__ bsum, int* __restrict__ bbase)
{
    __shared__ int sh[128];
    int t = threadIdx.x;
    int v = (t < NBLK) ? bsum[t] : 0;
    sh[t] = v;
    __syncthreads();
#pragma unroll
    for (int off = 1; off < 128; off <<= 1) {
        int u = (t >= off) ? sh[t - off] : 0;
        __syncthreads();
        sh[t] += u;
        __syncthreads();
    }
    if (t < NBLK) bbase[t] = sh[t] - v;
}

__global__ __launch_bounds__(256) void scan_apply(
    int* __restrict__ excl, const int* __restrict__ bbase,
    int* __restrict__ cursor)
{
    int t = threadIdx.x;
    int gid = blockIdx.x * 256 + t;
    if (gid < N_NODES) {
        int o = excl[gid] + bbase[blockIdx.x];
        excl[gid] = o;         // excl buffer IS offsets
        cursor[gid] = o;
    }
    if (blockIdx.x == 0 && t == 0) excl[N_NODES] = N_EDGES;
}

__global__ __launch_bounds__(256) void scatter_edges(
    const int* __restrict__ ei, int* __restrict__ cursor,
    int2* __restrict__ csr2)
{
    int e = blockIdx.x * 256 + threadIdx.x;
    if (e >= N_EDGES) return;
    int dst = ei[e];
    int src = ei[N_EDGES + e];
    int pos = atomicAdd(&cursor[dst], 1);
    csr2[pos] = make_int2(e, src);
}

// ---------------------------------------------------------------------------
// Fused attention v7: one wave per node, ONE (edge, head) PER LANE.
// lane = e_slot*8 + h (e_slot = lane>>3, h = lane&7). Each lane computes the
// full 16-dim dot serially (Q pre-unpacked to 16 floats), exp once per (e,h),
// accumulates p*V[src,h,:] into 16 registers. No per-edge shuffles at all.
// End-of-node: reduce-scatter butterfly over the 3 e_slot bits (8+4+2
// exchange-halving shuffles) leaves each lane holding 2 fully-reduced output
// dims; z full-reduced with 3 shuffles. exp without max-subtraction
// (identical softmax; logits are O(+-10)).
// ---------------------------------------------------------------------------
__global__ __launch_bounds__(256) void fused_attn(
    const ushort* __restrict__ Q2, const ushort* __restrict__ K2,
    const ushort* __restrict__ V2,
    const float* __restrict__ attn_bias,
    const int* __restrict__ offsets, const int2* __restrict__ csr2,
    float* __restrict__ logits, ushort* __restrict__ AGG)
{
    const int lane = threadIdx.x & 63;
    const int wid  = threadIdx.x >> 6;
    const int n = blockIdx.x * 4 + wid;
    const int start = offsets[n], end = offsets[n + 1];
    const int h  = lane & 7;
    const int es = lane >> 3;

    const uint4* Qu4 = reinterpret_cast<const uint4*>(Q2);
    const uint4* Ku4 = reinterpret_cast<const uint4*>(K2);
    const uint4* Vu4 = reinterpret_cast<const uint4*>(V2);

    // Q[n, h*16 .. +16) -> 16 floats (broadcast load across the 8 e_slots)
    uint4 qa = Qu4[n * 16 + h * 2];
    uint4 qb = Qu4[n * 16 + h * 2 + 1];
    float qf[16];
    {
        uint qq[8] = {qa.x, qa.y, qa.z, qa.w, qb.x, qb.y, qb.z, qb.w};
#pragma unroll
        for (int j = 0; j < 8; ++j) {
            qf[2 * j]     = bf16_lo(qq[j]);
            qf[2 * j + 1] = bf16_hi(qq[j]);
        }
    }

    float acc[16];
#pragma unroll
    for (int j = 0; j < 16; ++j) acc[j] = 0.f;
    float z = 0.f;

    for (int base = start; base < end; base += 8) {
        bool valid = (base + es) < end;
        int idx = base + es; if (!valid) idx = end - 1;
        int2 epair = csr2[idx];
        int e = epair.x, s = epair.y;

        uint4 k0 = Ku4[s * 16 + h * 2];
        uint4 k1 = Ku4[s * 16 + h * 2 + 1];
        uint4 v0 = Vu4[s * 16 + h * 2];
        uint4 v1 = Vu4[s * 16 + h * 2 + 1];
        float bias = attn_bias[e * 8 + h];

        uint kk[8] = {k0.x, k0.y, k0.z, k0.w, k1.x, k1.y, k1.z, k1.w};
        float d = 0.f;
#pragma unroll
        for (int j = 0; j < 8; ++j)
            d += qf[2 * j] * bf16_lo(kk[j]) + qf[2 * j + 1] * bf16_hi(kk[j]);

        float l = 0.25f * d + bias;
        float p = 0.f;
        if (valid) {
            logits[e * 8 + h] = l;
            p = __expf(l);
        }
        z += p;

        uint vv[8] = {v0.x, v0.y, v0.z, v0.w, v1.x, v1.y, v1.z, v1.w};
#pragma unroll
        for (int j = 0; j < 8; ++j) {
            acc[2 * j]     += p * bf16_lo(vv[j]);
            acc[2 * j + 1] += p * bf16_hi(vv[j]);
        }
    }

    // reduce-scatter butterfly over e_slot bits (lane bits 5,4,3)
    {
        int bit = (lane >> 5) & 1;
#pragma unroll
        for (int j = 0; j < 8; ++j) {
            float send = bit ? acc[j] : acc[j + 8];
            float keep = bit ? acc[j + 8] : acc[j];
            acc[j] = keep + __shfl_xor(send, 32, 64);
        }
        bit = (lane >> 4) & 1;
#pragma unroll
        for (int j = 0; j < 4; ++j) {
            float send = bit ? acc[j] : acc[j + 4];
            float keep = bit ? acc[j + 4] : acc[j];
            acc[j] = keep + __shfl_xor(send, 16, 64);
        }
        bit = (lane >> 3) & 1;
#pragma unroll
        for (int j = 0; j < 2; ++j) {
            float send = bit ? acc[j] : acc[j + 2];
            float keep = bit ? acc[j + 2] : acc[j];
            acc[j] = keep + __shfl_xor(send, 8, 64);
        }
    }
    z += __shfl_xor(z, 8, 64);
    z += __shfl_xor(z, 16, 64);
    z += __shfl_xor(z, 32, 64);

    float inv = (z > 0.f) ? 1.f / z : 0.f;
    // lane holds output dims h*16 + d_off + {0,1}
    int d_off = ((lane >> 5) & 1) * 8 + ((lane >> 4) & 1) * 4 + ((lane >> 3) & 1) * 2;
    reinterpret_cast<uint*>(AGG)[n * 64 + h * 8 + (d_off >> 1)] =
        pack2_bf16(acc[0] * inv, acc[1] * inv);
}

// ---------------------------------------------------------------------------
extern "C" void kernel_launch(void* const* d_in, const int* in_sizes, int n_in,
                              void* d_out, int out_size, void* d_ws, size_t ws_size,
                              hipStream_t stream)
{
    const float* x         = (const float*)d_in[0];
    const int*   ei        = (const int*)  d_in[1];
    const float* attn_bias = (const float*)d_in[2];
    const float* Wq = (const float*)d_in[3];
    const float* bq = (const float*)d_in[4];
    const float* Wk = (const float*)d_in[5];
    const float* bk = (const float*)d_in[6];
    const float* Wv = (const float*)d_in[7];
    const float* bv = (const float*)d_in[8];
    const float* Wo = (const float*)d_in[9];
    const float* bo = (const float*)d_in[10];

    float* out    = (float*)d_out;                // [N,128]
    float* logits = out + N_NODES * EMBED;        // [E,8] (output 1)

    ushort* xb   = (ushort*)d_ws;                 // N*128
    ushort* wb   = xb + NX;                       // 4*16384 (Wq,Wk,Wv,Wo)
    ushort* Qb   = wb + 4 * 16384;                // N*128
    ushort* Kb   = Qb + NX;                       // N*128
    ushort* Vb   = Kb + NX;                       // N*128
    ushort* AGGb = Vb + NX;                       // N*128
    int* deg     = (int*)(AGGb + NX);
    int* offsets = deg + N_NODES;                 // N+1 (also excl buffer)
    int* cursor  = offsets + N_NODES + 1;
    int2* csr2   = (int2*)(cursor + N_NODES);     // E pairs {edge, src}
    int* bsum    = (int*)(csr2 + N_EDGES);        // NBLK
    int* bbase   = bsum + NBLK;                   // NBLK

    int npairs = (NX + 4 * 16384) / 2;
    convert_all<<<(npairs + 255) / 256, 256, 0, stream>>>(x, Wq, Wk, Wv, Wo, xb, wb, deg);

    int gblocks = (N_NODES + 63) / 64;            // 391
    dim3 qkvgrid(gblocks, 4);                     // y=0..2 gemm, y=3 histogram
    gemm_qkv_deg<<<qkvgrid, 256, 0, stream>>>(xb, wb, bq, bk, bv, Qb, Kb, Vb,
                                              ei, deg, N_NODES);

    scan_blocks<<<NBLK, 256, 0, stream>>>(deg, offsets, bsum);
    scan_tops<<<1, 128, 0, stream>>>(bsum, bbase);
    scan_apply<<<NBLK, 256, 0, stream>>>(offsets, bbase, cursor);
    scatter_edges<<<(N_EDGES + 255) / 256, 256, 0, stream>>>(ei, cursor, csr2);

    fused_attn<<<N_NODES / 4, 256, 0, stream>>>(Qb, Kb, Vb, attn_bias,
                                                offsets, csr2, logits, AGGb);

    gemm_out<<<gblocks, 256, 0, stream>>>(AGGb, wb + 3 * 16384, bo, out, N_NODES);
}